// Round 1
// baseline (1043.060 us; speedup 1.0000x reference)
//
#include <hip/hip_runtime.h>

#define NN 50000
#define NE 800000
#define D  128
#define NG 64
#define BN_EPS 1e-5f

// ---------------- CSR build ----------------
__global__ void k_hist(const int* __restrict__ dst, int* __restrict__ counts) {
  int e = blockIdx.x * blockDim.x + threadIdx.x;
  if (e < NE) atomicAdd(&counts[dst[e]], 1);
}

__global__ void k_scan(const int* __restrict__ counts, int* __restrict__ offs) {
  __shared__ int wsum[16];
  __shared__ int carry_s;
  const int t = threadIdx.x, lane = t & 63, w = t >> 6;
  if (t == 0) carry_s = 0;
  __syncthreads();
  for (int base = 0; base < NN; base += 1024) {
    int i = base + t;
    int v = (i < NN) ? counts[i] : 0;
    int s = v;
    #pragma unroll
    for (int d = 1; d < 64; d <<= 1) { int u = __shfl_up(s, d, 64); if (lane >= d) s += u; }
    if (lane == 63) wsum[w] = s;
    __syncthreads();
    if (w == 0 && lane < 16) {
      int ws = wsum[lane]; int ss = ws;
      #pragma unroll
      for (int d = 1; d < 16; d <<= 1) { int u = __shfl_up(ss, d, 64); if (lane >= d) ss += u; }
      wsum[lane] = ss - ws;   // exclusive wave offsets
    }
    __syncthreads();
    int carry = carry_s;
    if (i < NN) offs[i] = carry + wsum[w] + (s - v);
    __syncthreads();
    if (t == 1023) carry_s = carry + wsum[15] + s;
    __syncthreads();
  }
  if (threadIdx.x == 0) offs[NN] = carry_s;
}

__global__ void k_scatter(const int* __restrict__ src, const int* __restrict__ dst,
                          const int* __restrict__ offs, int* __restrict__ cursor,
                          int* __restrict__ esrc) {
  int e = blockIdx.x * blockDim.x + threadIdx.x;
  if (e < NE) {
    int d = dst[e];
    int p = offs[d] + atomicAdd(&cursor[d], 1);
    esrc[p] = src[e];
  }
}

__global__ void k_ghist(const int* __restrict__ batch, int* __restrict__ gcnt) {
  int i = blockIdx.x * blockDim.x + threadIdx.x;
  if (i < NN) atomicAdd(&gcnt[batch[i]], 1);
}

__global__ void k_gscan(const int* __restrict__ gcnt, int* __restrict__ gstart) {
  const int l = threadIdx.x;            // 64 threads = 1 wave
  int v = gcnt[l];
  int s = v;
  #pragma unroll
  for (int d = 1; d < 64; d <<= 1) { int u = __shfl_up(s, d, 64); if (l >= d) s += u; }
  if (l == 0) gstart[0] = 0;
  gstart[l + 1] = s;
}

// ---------------- aggregation: AGG[n] = H[n] + sum_{e in CSR[n]} H[esrc[e]] ----------------
__global__ __launch_bounds__(256) void k_aggregate(const float* __restrict__ H,
                                                   const int* __restrict__ offs,
                                                   const int* __restrict__ esrc,
                                                   float* __restrict__ AGG) {
  const int node = blockIdx.x * 4 + (threadIdx.x >> 6);
  const int lane = threadIdx.x & 63;
  const float2* __restrict__ H2 = (const float2*)H;
  float2 acc = H2[node * 64 + lane];
  const int b = offs[node], e = offs[node + 1];
  for (int i = b; i < e; ++i) {
    const int s = esrc[i];
    const float2 v = H2[s * 64 + lane];
    acc.x += v.x; acc.y += v.y;
  }
  ((float2*)AGG)[node * 64 + lane] = acc;
}

// ---------------- fp32 GEMM: C[M x 128] = A[M x 128] @ W[128 x 128] + bias ----------------
// 128-row tile per block, 256 threads, each thread: 16 rows x 4 cols.
// In-place safe (A==C): block reads only its own rows; all loads precede stores.
template<bool RELU, bool STATS>
__global__ __launch_bounds__(256, 2) void k_gemm(const float* A, const float* __restrict__ W,
                                                 const float* __restrict__ bias, float* C,
                                                 float* __restrict__ sums, float* __restrict__ sumsq) {
  __shared__ float Al[32][132];   // [k][row], pad keeps 16B alignment per row
  __shared__ float Wl[32][128];
  const int t = threadIdx.x;
  const int tx = t & 31, ty = t >> 5;
  const int row0 = blockIdx.x * 128;
  const int f = t & 7, rr = t >> 3;

  float acc[16][4];
  #pragma unroll
  for (int i = 0; i < 16; ++i)
    #pragma unroll
    for (int jj = 0; jj < 4; ++jj) acc[i][jj] = 0.f;

  for (int k0 = 0; k0 < 128; k0 += 32) {
    #pragma unroll
    for (int jj = 0; jj < 4; ++jj) {
      const int r = rr + 32 * jj, gr = row0 + r;
      float4 v = make_float4(0.f, 0.f, 0.f, 0.f);
      if (gr < NN) v = *(const float4*)(A + (size_t)gr * D + k0 + f * 4);
      Al[f*4+0][r] = v.x; Al[f*4+1][r] = v.y; Al[f*4+2][r] = v.z; Al[f*4+3][r] = v.w;
    }
    #pragma unroll
    for (int jj = 0; jj < 4; ++jj) {
      const int col4 = (f + 8 * jj) * 4;
      *(float4*)&Wl[rr][col4] = *(const float4*)(W + (size_t)(k0 + rr) * D + col4);
    }
    __syncthreads();
    #pragma unroll
    for (int k = 0; k < 32; ++k) {
      const float4 wv = *(const float4*)&Wl[k][tx * 4];
      #pragma unroll
      for (int iq = 0; iq < 4; ++iq) {
        const float4 av = *(const float4*)&Al[k][ty * 16 + iq * 4];
        const float a4[4] = {av.x, av.y, av.z, av.w};
        #pragma unroll
        for (int ii = 0; ii < 4; ++ii) {
          acc[iq*4+ii][0] = fmaf(a4[ii], wv.x, acc[iq*4+ii][0]);
          acc[iq*4+ii][1] = fmaf(a4[ii], wv.y, acc[iq*4+ii][1]);
          acc[iq*4+ii][2] = fmaf(a4[ii], wv.z, acc[iq*4+ii][2]);
          acc[iq*4+ii][3] = fmaf(a4[ii], wv.w, acc[iq*4+ii][3]);
        }
      }
    }
    __syncthreads();
  }

  const float4 b4 = *(const float4*)(bias + tx * 4);
  float ps[4] = {0.f,0.f,0.f,0.f}, pq[4] = {0.f,0.f,0.f,0.f};
  #pragma unroll
  for (int i = 0; i < 16; ++i) {
    const int gr = row0 + ty * 16 + i;
    if (gr < NN) {
      float4 cv;
      cv.x = acc[i][0] + b4.x; cv.y = acc[i][1] + b4.y;
      cv.z = acc[i][2] + b4.z; cv.w = acc[i][3] + b4.w;
      if (RELU) {
        cv.x = fmaxf(cv.x, 0.f); cv.y = fmaxf(cv.y, 0.f);
        cv.z = fmaxf(cv.z, 0.f); cv.w = fmaxf(cv.w, 0.f);
      }
      *(float4*)(C + (size_t)gr * D + tx * 4) = cv;
      if (STATS) {
        ps[0] += cv.x; pq[0] += cv.x * cv.x;
        ps[1] += cv.y; pq[1] += cv.y * cv.y;
        ps[2] += cv.z; pq[2] += cv.z * cv.z;
        ps[3] += cv.w; pq[3] += cv.w * cv.w;
      }
    }
  }
  if (STATS) {
    __syncthreads();
    float* red  = &Al[0][0];      // reuse LDS: need 2048 floats, have 4224
    float* redq = red + 1024;
    #pragma unroll
    for (int jj = 0; jj < 4; ++jj) {
      red [ty * 128 + tx * 4 + jj] = ps[jj];
      redq[ty * 128 + tx * 4 + jj] = pq[jj];
    }
    __syncthreads();
    if (ty == 0) {
      #pragma unroll
      for (int jj = 0; jj < 4; ++jj) {
        const int col = tx * 4 + jj;
        float ssum = 0.f, ssq = 0.f;
        #pragma unroll
        for (int yy = 0; yy < 8; ++yy) { ssum += red[yy * 128 + col]; ssq += redq[yy * 128 + col]; }
        atomicAdd(&sums[col], ssum);
        atomicAdd(&sumsq[col], ssq);
      }
    }
  }
}

// ---------------- BN ----------------
__global__ void k_stats(const float* __restrict__ sums, const float* __restrict__ sumsq,
                        const float* __restrict__ g, const float* __restrict__ beta,
                        float* __restrict__ scale, float* __restrict__ shift) {
  const int c = threadIdx.x;
  const float m   = sums[c] / (float)NN;
  const float var = sumsq[c] / (float)NN - m * m;
  const float sc  = g[c] / sqrtf(var + BN_EPS);
  scale[c] = sc;
  shift[c] = beta[c] - m * sc;
}

__global__ __launch_bounds__(256) void k_bnrelu(const float* __restrict__ T,
                                                const float* __restrict__ scale,
                                                const float* __restrict__ shift,
                                                float* __restrict__ O) {
  const int n4 = NN * D / 4;
  for (int i = blockIdx.x * blockDim.x + threadIdx.x; i < n4; i += gridDim.x * blockDim.x) {
    float4 v = ((const float4*)T)[i];
    const int c4 = (i & 31) * 4;
    const float4 sc = *(const float4*)(scale + c4);
    const float4 sh = *(const float4*)(shift + c4);
    float4 o;
    o.x = fmaxf(fmaf(v.x, sc.x, sh.x), 0.f);
    o.y = fmaxf(fmaf(v.y, sc.y, sh.y), 0.f);
    o.z = fmaxf(fmaf(v.z, sc.z, sh.z), 0.f);
    o.w = fmaxf(fmaf(v.w, sc.w, sh.w), 0.f);
    ((float4*)O)[i] = o;
  }
}

// ---------------- pooling (sum; division folded into fc1) ----------------
__global__ __launch_bounds__(256) void k_pool(const float* __restrict__ H,
                                              const int* __restrict__ gstart,
                                              float* __restrict__ pooled, int lofs) {
  const int g = blockIdx.y;
  const int s = gstart[g], e = gstart[g + 1];
  const int t = threadIdx.x, c = t & 127, half = t >> 7;
  const int len = e - s;
  const int nchunk = (int)gridDim.x;
  const int per = (len + nchunk - 1) / nchunk;
  const int r0 = s + (int)blockIdx.x * per;
  const int r1 = min(e, r0 + per);
  float sum = 0.f;
  for (int r = r0 + half; r < r1; r += 2) sum += H[r * D + c];
  __shared__ float red[256];
  red[t] = sum;
  __syncthreads();
  if (t < 128) atomicAdd(&pooled[g * 384 + lofs + c], red[t] + red[t + 128]);
}

// ---------------- prediction head ----------------
__global__ __launch_bounds__(128) void k_fc1(const float* __restrict__ pooled,
                                             const int* __restrict__ gcnt,
                                             const float* __restrict__ W1,
                                             const float* __restrict__ b1,
                                             float* __restrict__ z1) {
  const int g = blockIdx.x, j = threadIdx.x;
  __shared__ float p[384];
  const float inv = 1.f / fmaxf((float)gcnt[g], 1.f);
  for (int k = j; k < 384; k += 128) p[k] = pooled[g * 384 + k] * inv;
  __syncthreads();
  float acc = b1[j];
  #pragma unroll 8
  for (int k = 0; k < 384; ++k) acc = fmaf(p[k], W1[k * 128 + j], acc);
  z1[g * 128 + j] = fmaxf(acc, 0.f);
}

__global__ __launch_bounds__(128) void k_head(const float* __restrict__ z1,
                                              const float* __restrict__ g,
                                              const float* __restrict__ beta,
                                              const float* __restrict__ W2,
                                              const float* __restrict__ b2,
                                              float* __restrict__ out) {
  __shared__ float z2[NG][129];
  __shared__ float w2s[128];
  const int j = threadIdx.x;
  w2s[j] = W2[j];
  float vals[NG];
  float s = 0.f, q = 0.f;
  for (int gg = 0; gg < NG; ++gg) {
    float v = z1[gg * 128 + j];
    vals[gg] = v; s += v; q += v * v;
  }
  const float m   = s / (float)NG;
  const float var = q / (float)NG - m * m;
  const float sc  = g[j] / sqrtf(var + BN_EPS);
  const float sh  = beta[j] - m * sc;
  for (int gg = 0; gg < NG; ++gg) z2[gg][j] = vals[gg] * sc + sh;
  __syncthreads();
  if (j < NG) {
    float acc = b2[0];
    #pragma unroll 8
    for (int k = 0; k < 128; ++k) acc += z2[j][k] * w2s[k];
    out[j] = acc;
  }
}

// ---------------- launch ----------------
extern "C" void kernel_launch(void* const* d_in, const int* in_sizes, int n_in,
                              void* d_out, int out_size, void* d_ws, size_t ws_size,
                              hipStream_t stream) {
  const float* x     = (const float*)d_in[0];
  const int*   e_src = (const int*)d_in[1];        // edge_index row 0
  const int*   e_dst = e_src + NE;                 // edge_index row 1
  const int*   batch = (const int*)d_in[2];
  const float *lW1[3], *lb1[3], *lW2[3], *lb2[3], *lg[3], *lbeta[3];
  for (int l = 0; l < 3; ++l) {
    lW1[l]   = (const float*)d_in[3 + 6 * l + 0];
    lb1[l]   = (const float*)d_in[3 + 6 * l + 1];
    lW2[l]   = (const float*)d_in[3 + 6 * l + 2];
    lb2[l]   = (const float*)d_in[3 + 6 * l + 3];
    lg[l]    = (const float*)d_in[3 + 6 * l + 4];
    lbeta[l] = (const float*)d_in[3 + 6 * l + 5];
  }
  const float* pW1   = (const float*)d_in[21];
  const float* pb1   = (const float*)d_in[22];
  const float* pg    = (const float*)d_in[23];
  const float* pbeta = (const float*)d_in[24];
  const float* pW2   = (const float*)d_in[25];
  const float* pb2   = (const float*)d_in[26];
  float* out = (float*)d_out;

  char* w = (char*)d_ws;
  auto alloc = [&](size_t bytes) { char* p = w; w += (bytes + 255) & ~(size_t)255; return p; };
  float* P      = (float*)alloc((size_t)NN * D * 4);
  float* Q      = (float*)alloc((size_t)NN * D * 4);
  int*   counts = (int*)alloc((size_t)NN * 4);
  int*   cursor = (int*)alloc((size_t)NN * 4);
  int*   offs   = (int*)alloc((size_t)(NN + 1) * 4);
  int*   esrc   = (int*)alloc((size_t)NE * 4);
  int*   gcnt   = (int*)alloc((size_t)NG * 4);
  int*   gstart = (int*)alloc((size_t)(NG + 1) * 4);
  float* stats  = (float*)alloc((size_t)4 * 128 * 4);
  float* sums = stats, *sumsq = stats + 128, *scale = stats + 256, *shift = stats + 384;
  float* pooled = (float*)alloc((size_t)NG * 384 * 4);
  float* z1     = (float*)alloc((size_t)NG * 128 * 4);

  hipMemsetAsync(counts, 0, (size_t)NN * 4, stream);
  hipMemsetAsync(cursor, 0, (size_t)NN * 4, stream);
  hipMemsetAsync(gcnt,   0, (size_t)NG * 4, stream);
  hipMemsetAsync(pooled, 0, (size_t)NG * 384 * 4, stream);

  k_hist   <<<(NE + 255) / 256, 256, 0, stream>>>(e_dst, counts);
  k_scan   <<<1, 1024, 0, stream>>>(counts, offs);
  k_scatter<<<(NE + 255) / 256, 256, 0, stream>>>(e_src, e_dst, offs, cursor, esrc);
  k_ghist  <<<(NN + 255) / 256, 256, 0, stream>>>(batch, gcnt);
  k_gscan  <<<1, 64, 0, stream>>>(gcnt, gstart);

  const float* Hin = x;
  for (int l = 0; l < 3; ++l) {
    k_aggregate<<<NN / 4, 256, 0, stream>>>(Hin, offs, esrc, Q);
    k_gemm<true, false><<<(NN + 127) / 128, 256, 0, stream>>>(Q, lW1[l], lb1[l], Q, nullptr, nullptr);
    hipMemsetAsync(sums, 0, 2 * 128 * 4, stream);
    k_gemm<false, true><<<(NN + 127) / 128, 256, 0, stream>>>(Q, lW2[l], lb2[l], Q, sums, sumsq);
    k_stats <<<1, 128, 0, stream>>>(sums, sumsq, lg[l], lbeta[l], scale, shift);
    k_bnrelu<<<2048, 256, 0, stream>>>(Q, scale, shift, P);
    k_pool  <<<dim3(8, NG), 256, 0, stream>>>(P, gstart, pooled, l * 128);
    Hin = P;
  }

  k_fc1 <<<NG, 128, 0, stream>>>(pooled, gcnt, pW1, pb1, z1);
  k_head<<<1, 128, 0, stream>>>(z1, pg, pbeta, pW2, pb2, out);
}

// Round 2
// 800.426 us; speedup vs baseline: 1.3031x; 1.3031x over previous
//
#include <hip/hip_runtime.h>

#define NN 50000
#define NE 800000
#define D  128
#define NG 64
#define BN_EPS 1e-5f

// ---------------- CSR build ----------------
__global__ void k_hist(const int* __restrict__ dst, int* __restrict__ counts) {
  int e = blockIdx.x * blockDim.x + threadIdx.x;
  if (e < NE) atomicAdd(&counts[dst[e]], 1);
}

__global__ void k_scan(const int* __restrict__ counts, int* __restrict__ offs) {
  __shared__ int wsum[16];
  __shared__ int carry_s;
  const int t = threadIdx.x, lane = t & 63, w = t >> 6;
  if (t == 0) carry_s = 0;
  __syncthreads();
  for (int base = 0; base < NN; base += 1024) {
    int i = base + t;
    int v = (i < NN) ? counts[i] : 0;
    int s = v;
    #pragma unroll
    for (int d = 1; d < 64; d <<= 1) { int u = __shfl_up(s, d, 64); if (lane >= d) s += u; }
    if (lane == 63) wsum[w] = s;
    __syncthreads();
    if (w == 0 && lane < 16) {
      int ws = wsum[lane]; int ss = ws;
      #pragma unroll
      for (int d = 1; d < 16; d <<= 1) { int u = __shfl_up(ss, d, 64); if (lane >= d) ss += u; }
      wsum[lane] = ss - ws;   // exclusive wave offsets
    }
    __syncthreads();
    int carry = carry_s;
    if (i < NN) offs[i] = carry + wsum[w] + (s - v);
    __syncthreads();
    if (t == 1023) carry_s = carry + wsum[15] + s;
    __syncthreads();
  }
  if (threadIdx.x == 0) offs[NN] = carry_s;
}

__global__ void k_scatter(const int* __restrict__ src, const int* __restrict__ dst,
                          const int* __restrict__ offs, int* __restrict__ cursor,
                          int* __restrict__ esrc) {
  int e = blockIdx.x * blockDim.x + threadIdx.x;
  if (e < NE) {
    int d = dst[e];
    int p = offs[d] + atomicAdd(&cursor[d], 1);
    esrc[p] = src[e];
  }
}

// batch is sorted: per-graph segment bounds via binary search (replaces the
// 235us atomic-contention k_ghist).
__global__ void k_gbounds(const int* __restrict__ batch, int* __restrict__ gstart) {
  const int g = threadIdx.x;
  if (g > NG) return;
  int lo = 0, hi = NN;
  while (lo < hi) { int mid = (lo + hi) >> 1; if (batch[mid] < g) lo = mid + 1; else hi = mid; }
  gstart[g] = lo;
}

// ---------------- aggregation: AGG[n] = H[n] + sum_{e in CSR[n]} H[esrc[e]] ----------------
__global__ __launch_bounds__(256) void k_aggregate(const float* __restrict__ H,
                                                   const int* __restrict__ offs,
                                                   const int* __restrict__ esrc,
                                                   float* __restrict__ AGG) {
  const int node = blockIdx.x * 4 + (threadIdx.x >> 6);
  const int lane = threadIdx.x & 63;
  const float2* __restrict__ H2 = (const float2*)H;
  float2 acc = H2[node * 64 + lane];
  const int b = offs[node], e = offs[node + 1];
  for (int i = b; i < e; ++i) {
    const int s = esrc[i];
    const float2 v = H2[s * 64 + lane];
    acc.x += v.x; acc.y += v.y;
  }
  ((float2*)AGG)[node * 64 + lane] = acc;
}

// ---------------- fp32 GEMM: C[M x 128] = A[M x 128] @ W[128 x 128] + bias ----------------
// 128-row tile per block, 256 threads, each thread: 16 rows x 4 cols.
// In-place safe (A==C): block reads only its own rows; all loads precede stores.
template<bool RELU, bool STATS>
__global__ __launch_bounds__(256, 2) void k_gemm(const float* A, const float* __restrict__ W,
                                                 const float* __restrict__ bias, float* C,
                                                 float* __restrict__ sums, float* __restrict__ sumsq) {
  __shared__ float Al[32][132];   // [k][row], pad keeps 16B alignment per row
  __shared__ float Wl[32][128];
  const int t = threadIdx.x;
  const int tx = t & 31, ty = t >> 5;
  const int row0 = blockIdx.x * 128;
  const int f = t & 7, rr = t >> 3;

  float acc[16][4];
  #pragma unroll
  for (int i = 0; i < 16; ++i)
    #pragma unroll
    for (int jj = 0; jj < 4; ++jj) acc[i][jj] = 0.f;

  for (int k0 = 0; k0 < 128; k0 += 32) {
    #pragma unroll
    for (int jj = 0; jj < 4; ++jj) {
      const int r = rr + 32 * jj, gr = row0 + r;
      float4 v = make_float4(0.f, 0.f, 0.f, 0.f);
      if (gr < NN) v = *(const float4*)(A + (size_t)gr * D + k0 + f * 4);
      Al[f*4+0][r] = v.x; Al[f*4+1][r] = v.y; Al[f*4+2][r] = v.z; Al[f*4+3][r] = v.w;
    }
    #pragma unroll
    for (int jj = 0; jj < 4; ++jj) {
      const int col4 = (f + 8 * jj) * 4;
      *(float4*)&Wl[rr][col4] = *(const float4*)(W + (size_t)(k0 + rr) * D + col4);
    }
    __syncthreads();
    #pragma unroll
    for (int k = 0; k < 32; ++k) {
      const float4 wv = *(const float4*)&Wl[k][tx * 4];
      #pragma unroll
      for (int iq = 0; iq < 4; ++iq) {
        const float4 av = *(const float4*)&Al[k][ty * 16 + iq * 4];
        const float a4[4] = {av.x, av.y, av.z, av.w};
        #pragma unroll
        for (int ii = 0; ii < 4; ++ii) {
          acc[iq*4+ii][0] = fmaf(a4[ii], wv.x, acc[iq*4+ii][0]);
          acc[iq*4+ii][1] = fmaf(a4[ii], wv.y, acc[iq*4+ii][1]);
          acc[iq*4+ii][2] = fmaf(a4[ii], wv.z, acc[iq*4+ii][2]);
          acc[iq*4+ii][3] = fmaf(a4[ii], wv.w, acc[iq*4+ii][3]);
        }
      }
    }
    __syncthreads();
  }

  const float4 b4 = *(const float4*)(bias + tx * 4);
  float ps[4] = {0.f,0.f,0.f,0.f}, pq[4] = {0.f,0.f,0.f,0.f};
  #pragma unroll
  for (int i = 0; i < 16; ++i) {
    const int gr = row0 + ty * 16 + i;
    if (gr < NN) {
      float4 cv;
      cv.x = acc[i][0] + b4.x; cv.y = acc[i][1] + b4.y;
      cv.z = acc[i][2] + b4.z; cv.w = acc[i][3] + b4.w;
      if (RELU) {
        cv.x = fmaxf(cv.x, 0.f); cv.y = fmaxf(cv.y, 0.f);
        cv.z = fmaxf(cv.z, 0.f); cv.w = fmaxf(cv.w, 0.f);
      }
      *(float4*)(C + (size_t)gr * D + tx * 4) = cv;
      if (STATS) {
        ps[0] += cv.x; pq[0] += cv.x * cv.x;
        ps[1] += cv.y; pq[1] += cv.y * cv.y;
        ps[2] += cv.z; pq[2] += cv.z * cv.z;
        ps[3] += cv.w; pq[3] += cv.w * cv.w;
      }
    }
  }
  if (STATS) {
    __syncthreads();
    float* red  = &Al[0][0];      // reuse LDS: need 2048 floats, have 4224
    float* redq = red + 1024;
    #pragma unroll
    for (int jj = 0; jj < 4; ++jj) {
      red [ty * 128 + tx * 4 + jj] = ps[jj];
      redq[ty * 128 + tx * 4 + jj] = pq[jj];
    }
    __syncthreads();
    if (ty == 0) {
      #pragma unroll
      for (int jj = 0; jj < 4; ++jj) {
        const int col = tx * 4 + jj;
        float ssum = 0.f, ssq = 0.f;
        #pragma unroll
        for (int yy = 0; yy < 8; ++yy) { ssum += red[yy * 128 + col]; ssq += redq[yy * 128 + col]; }
        atomicAdd(&sums[col], ssum);
        atomicAdd(&sumsq[col], ssq);
      }
    }
  }
}

// ---------------- BN ----------------
__global__ void k_stats(const float* __restrict__ sums, const float* __restrict__ sumsq,
                        const float* __restrict__ g, const float* __restrict__ beta,
                        float* __restrict__ scale, float* __restrict__ shift) {
  const int c = threadIdx.x;
  const float m   = sums[c] / (float)NN;
  const float var = sumsq[c] / (float)NN - m * m;
  const float sc  = g[c] / sqrtf(var + BN_EPS);
  scale[c] = sc;
  shift[c] = beta[c] - m * sc;
}

__global__ __launch_bounds__(256) void k_bnrelu(const float* __restrict__ T,
                                                const float* __restrict__ scale,
                                                const float* __restrict__ shift,
                                                float* __restrict__ O) {
  const int n4 = NN * D / 4;
  for (int i = blockIdx.x * blockDim.x + threadIdx.x; i < n4; i += gridDim.x * blockDim.x) {
    float4 v = ((const float4*)T)[i];
    const int c4 = (i & 31) * 4;
    const float4 sc = *(const float4*)(scale + c4);
    const float4 sh = *(const float4*)(shift + c4);
    float4 o;
    o.x = fmaxf(fmaf(v.x, sc.x, sh.x), 0.f);
    o.y = fmaxf(fmaf(v.y, sc.y, sh.y), 0.f);
    o.z = fmaxf(fmaf(v.z, sc.z, sh.z), 0.f);
    o.w = fmaxf(fmaf(v.w, sc.w, sh.w), 0.f);
    ((float4*)O)[i] = o;
  }
}

// ---------------- pooling (sum; division folded into fc1) ----------------
__global__ __launch_bounds__(256) void k_pool(const float* __restrict__ H,
                                              const int* __restrict__ gstart,
                                              float* __restrict__ pooled, int lofs) {
  const int g = blockIdx.y;
  const int s = gstart[g], e = gstart[g + 1];
  const int t = threadIdx.x, c = t & 127, half = t >> 7;
  const int len = e - s;
  const int nchunk = (int)gridDim.x;
  const int per = (len + nchunk - 1) / nchunk;
  const int r0 = s + (int)blockIdx.x * per;
  const int r1 = min(e, r0 + per);
  float sum = 0.f;
  for (int r = r0 + half; r < r1; r += 2) sum += H[r * D + c];
  __shared__ float red[256];
  red[t] = sum;
  __syncthreads();
  if (t < 128) atomicAdd(&pooled[g * 384 + lofs + c], red[t] + red[t + 128]);
}

// ---------------- prediction head ----------------
__global__ __launch_bounds__(128) void k_fc1(const float* __restrict__ pooled,
                                             const int* __restrict__ gstart,
                                             const float* __restrict__ W1,
                                             const float* __restrict__ b1,
                                             float* __restrict__ z1) {
  const int g = blockIdx.x, j = threadIdx.x;
  __shared__ float p[384];
  const float cnt = (float)(gstart[g + 1] - gstart[g]);
  const float inv = 1.f / fmaxf(cnt, 1.f);
  for (int k = j; k < 384; k += 128) p[k] = pooled[g * 384 + k] * inv;
  __syncthreads();
  float acc = b1[j];
  #pragma unroll 8
  for (int k = 0; k < 384; ++k) acc = fmaf(p[k], W1[k * 128 + j], acc);
  z1[g * 128 + j] = fmaxf(acc, 0.f);
}

__global__ __launch_bounds__(128) void k_head(const float* __restrict__ z1,
                                              const float* __restrict__ g,
                                              const float* __restrict__ beta,
                                              const float* __restrict__ W2,
                                              const float* __restrict__ b2,
                                              float* __restrict__ out) {
  __shared__ float z2[NG][129];
  __shared__ float w2s[128];
  const int j = threadIdx.x;
  w2s[j] = W2[j];
  float vals[NG];
  float s = 0.f, q = 0.f;
  for (int gg = 0; gg < NG; ++gg) {
    float v = z1[gg * 128 + j];
    vals[gg] = v; s += v; q += v * v;
  }
  const float m   = s / (float)NG;
  const float var = q / (float)NG - m * m;
  const float sc  = g[j] / sqrtf(var + BN_EPS);
  const float sh  = beta[j] - m * sc;
  for (int gg = 0; gg < NG; ++gg) z2[gg][j] = vals[gg] * sc + sh;
  __syncthreads();
  if (j < NG) {
    float acc = b2[0];
    #pragma unroll 8
    for (int k = 0; k < 128; ++k) acc += z2[j][k] * w2s[k];
    out[j] = acc;
  }
}

// ---------------- launch ----------------
extern "C" void kernel_launch(void* const* d_in, const int* in_sizes, int n_in,
                              void* d_out, int out_size, void* d_ws, size_t ws_size,
                              hipStream_t stream) {
  const float* x     = (const float*)d_in[0];
  const int*   e_src = (const int*)d_in[1];        // edge_index row 0
  const int*   e_dst = e_src + NE;                 // edge_index row 1
  const int*   batch = (const int*)d_in[2];
  const float *lW1[3], *lb1[3], *lW2[3], *lb2[3], *lg[3], *lbeta[3];
  for (int l = 0; l < 3; ++l) {
    lW1[l]   = (const float*)d_in[3 + 6 * l + 0];
    lb1[l]   = (const float*)d_in[3 + 6 * l + 1];
    lW2[l]   = (const float*)d_in[3 + 6 * l + 2];
    lb2[l]   = (const float*)d_in[3 + 6 * l + 3];
    lg[l]    = (const float*)d_in[3 + 6 * l + 4];
    lbeta[l] = (const float*)d_in[3 + 6 * l + 5];
  }
  const float* pW1   = (const float*)d_in[21];
  const float* pb1   = (const float*)d_in[22];
  const float* pg    = (const float*)d_in[23];
  const float* pbeta = (const float*)d_in[24];
  const float* pW2   = (const float*)d_in[25];
  const float* pb2   = (const float*)d_in[26];
  float* out = (float*)d_out;

  char* w = (char*)d_ws;
  auto alloc = [&](size_t bytes) { char* p = w; w += (bytes + 255) & ~(size_t)255; return p; };
  float* P      = (float*)alloc((size_t)NN * D * 4);
  float* Q      = (float*)alloc((size_t)NN * D * 4);
  int*   counts = (int*)alloc((size_t)NN * 4);
  int*   cursor = (int*)alloc((size_t)NN * 4);
  int*   offs   = (int*)alloc((size_t)(NN + 1) * 4);
  int*   esrc   = (int*)alloc((size_t)NE * 4);
  int*   gstart = (int*)alloc((size_t)(NG + 1) * 4);
  float* stats  = (float*)alloc((size_t)4 * 128 * 4);
  float* sums = stats, *sumsq = stats + 128, *scale = stats + 256, *shift = stats + 384;
  float* pooled = (float*)alloc((size_t)NG * 384 * 4);
  float* z1     = (float*)alloc((size_t)NG * 128 * 4);

  hipMemsetAsync(counts, 0, (size_t)NN * 4, stream);
  hipMemsetAsync(cursor, 0, (size_t)NN * 4, stream);
  hipMemsetAsync(pooled, 0, (size_t)NG * 384 * 4, stream);

  k_hist   <<<(NE + 255) / 256, 256, 0, stream>>>(e_dst, counts);
  k_scan   <<<1, 1024, 0, stream>>>(counts, offs);
  k_scatter<<<(NE + 255) / 256, 256, 0, stream>>>(e_src, e_dst, offs, cursor, esrc);
  k_gbounds<<<1, 128, 0, stream>>>(batch, gstart);

  const float* Hin = x;
  for (int l = 0; l < 3; ++l) {
    k_aggregate<<<NN / 4, 256, 0, stream>>>(Hin, offs, esrc, Q);
    k_gemm<true, false><<<(NN + 127) / 128, 256, 0, stream>>>(Q, lW1[l], lb1[l], Q, nullptr, nullptr);
    hipMemsetAsync(sums, 0, 2 * 128 * 4, stream);
    k_gemm<false, true><<<(NN + 127) / 128, 256, 0, stream>>>(Q, lW2[l], lb2[l], Q, sums, sumsq);
    k_stats <<<1, 128, 0, stream>>>(sums, sumsq, lg[l], lbeta[l], scale, shift);
    k_bnrelu<<<2048, 256, 0, stream>>>(Q, scale, shift, P);
    k_pool  <<<dim3(8, NG), 256, 0, stream>>>(P, gstart, pooled, l * 128);
    Hin = P;
  }

  k_fc1 <<<NG, 128, 0, stream>>>(pooled, gstart, pW1, pb1, z1);
  k_head<<<1, 128, 0, stream>>>(z1, pg, pbeta, pW2, pb2, out);
}

// Round 3
// 632.161 us; speedup vs baseline: 1.6500x; 1.2662x over previous
//
#include <hip/hip_runtime.h>

#define NN 50000
#define NE 800000
#define D  128
#define NG 64
#define BN_EPS 1e-5f

typedef __attribute__((ext_vector_type(8))) short short8;
typedef __attribute__((ext_vector_type(4))) float f32x4;
typedef __attribute__((ext_vector_type(2))) unsigned long long u64x2;

static __device__ inline unsigned short f2bf_rn(float f) {
  unsigned u = __float_as_uint(f);
  unsigned r = (u + 0x7FFF + ((u >> 16) & 1)) >> 16;
  return (unsigned short)r;
}
static __device__ inline float bf2f(unsigned short h) {
  return __uint_as_float((unsigned)h << 16);
}

// ---------------- CSR build ----------------
__global__ void k_hist(const int* __restrict__ dst, int* __restrict__ counts) {
  int e = blockIdx.x * blockDim.x + threadIdx.x;
  if (e < NE) atomicAdd(&counts[dst[e]], 1);
}

__global__ void k_scan(const int* __restrict__ counts, int* __restrict__ offs) {
  __shared__ int wsum[16];
  __shared__ int carry_s;
  const int t = threadIdx.x, lane = t & 63, w = t >> 6;
  if (t == 0) carry_s = 0;
  __syncthreads();
  for (int base = 0; base < NN; base += 1024) {
    int i = base + t;
    int v = (i < NN) ? counts[i] : 0;
    int s = v;
    #pragma unroll
    for (int d = 1; d < 64; d <<= 1) { int u = __shfl_up(s, d, 64); if (lane >= d) s += u; }
    if (lane == 63) wsum[w] = s;
    __syncthreads();
    if (w == 0 && lane < 16) {
      int ws = wsum[lane]; int ss = ws;
      #pragma unroll
      for (int d = 1; d < 16; d <<= 1) { int u = __shfl_up(ss, d, 64); if (lane >= d) ss += u; }
      wsum[lane] = ss - ws;
    }
    __syncthreads();
    int carry = carry_s;
    if (i < NN) offs[i] = carry + wsum[w] + (s - v);
    __syncthreads();
    if (t == 1023) carry_s = carry + wsum[15] + s;
    __syncthreads();
  }
  if (threadIdx.x == 0) offs[NN] = carry_s;
}

__global__ void k_scatter(const int* __restrict__ src, const int* __restrict__ dst,
                          const int* __restrict__ offs, int* __restrict__ cursor,
                          int* __restrict__ esrc) {
  int e = blockIdx.x * blockDim.x + threadIdx.x;
  if (e < NE) {
    int d = dst[e];
    int p = offs[d] + atomicAdd(&cursor[d], 1);
    esrc[p] = src[e];
  }
}

__global__ void k_gbounds(const int* __restrict__ batch, int* __restrict__ gstart) {
  const int g = threadIdx.x;
  if (g > NG) return;
  int lo = 0, hi = NN;
  while (lo < hi) { int mid = (lo + hi) >> 1; if (batch[mid] < g) lo = mid + 1; else hi = mid; }
  gstart[g] = lo;
}

// ---------------- weight prep: W[128][128] fp32 -> W^T hi/lo bf16, chunked+padded ----------------
// Output layout: [chunk(4)][col(128)][40] shorts; element (k,c) -> plane[(k>>5)*128+c][k&31].
__global__ void k_prep(const float* __restrict__ W, short* __restrict__ WhT,
                       short* __restrict__ WlT) {
  const int t = threadIdx.x;
  for (int i = 0; i < 64; ++i) {
    int idx = i * 256 + t;             // 16384 elems
    int k = idx >> 7, c = idx & 127;
    float v = W[idx];
    unsigned short h = f2bf_rn(v);
    unsigned short lo = f2bf_rn(v - bf2f(h));
    int o = ((k >> 5) * 128 + c) * 40 + (k & 31);
    WhT[o] = (short)h;
    WlT[o] = (short)lo;
  }
}

// ---------------- aggregation (+ fused BN/ReLU of the producer layer) ----------------
template<bool BN>
__global__ __launch_bounds__(256) void k_aggregate(const float* __restrict__ H,
                                                   const int* __restrict__ offs,
                                                   const int* __restrict__ esrc,
                                                   const float* __restrict__ scale,
                                                   const float* __restrict__ shift,
                                                   float* __restrict__ AGG) {
  const int node = blockIdx.x * 4 + (threadIdx.x >> 6);
  const int lane = threadIdx.x & 63;
  const float2* __restrict__ H2 = (const float2*)H;
  float2 sc = make_float2(1.f, 1.f), sh = make_float2(0.f, 0.f);
  if (BN) { sc = ((const float2*)scale)[lane]; sh = ((const float2*)shift)[lane]; }

  auto rd = [&](int r) -> float2 {
    float2 v = H2[r * 64 + lane];
    if (BN) {
      v.x = fmaxf(fmaf(v.x, sc.x, sh.x), 0.f);
      v.y = fmaxf(fmaf(v.y, sc.y, sh.y), 0.f);
    }
    return v;
  };

  float2 acc = rd(node);
  const int b = offs[node], e = offs[node + 1];
  int i = b;
  for (; i + 4 <= e; i += 4) {
    const int s0 = esrc[i], s1 = esrc[i + 1], s2 = esrc[i + 2], s3 = esrc[i + 3];
    const float2 v0 = rd(s0), v1 = rd(s1), v2 = rd(s2), v3 = rd(s3);
    acc.x += (v0.x + v1.x) + (v2.x + v3.x);
    acc.y += (v0.y + v1.y) + (v2.y + v3.y);
  }
  for (; i < e; ++i) {
    const float2 v = rd(esrc[i]);
    acc.x += v.x; acc.y += v.y;
  }
  ((float2*)AGG)[node * 64 + lane] = acc;
}

// ---------------- MFMA GEMM: C[M x 128] = A[M x 128] @ W + bias, hi/lo bf16 split ----------------
// 128 rows/block, 4 waves (2 row-tiles each), K chunked by 32. In-place safe.
template<bool RELU, bool STATS>
__global__ __launch_bounds__(256, 2) void k_gemm_mfma(const float* A,
                                                      const short* __restrict__ WhT,
                                                      const short* __restrict__ WlT,
                                                      const float* __restrict__ bias, float* C,
                                                      float* __restrict__ sums,
                                                      float* __restrict__ sumsq) {
  __shared__ __align__(16) char SMEM[40960];
  short* sAh = (short*)SMEM;                 // [128][40]
  short* sAl = (short*)(SMEM + 10240);
  short* sBh = (short*)(SMEM + 20480);       // [128 cols][40]
  short* sBl = (short*)(SMEM + 30720);

  const int t = threadIdx.x;
  const int l = t & 63, w = t >> 6;
  const int lr = l & 15;                     // row-in-tile (A) / col-in-tile (B,D)
  const int lk = (l >> 4) * 8;               // k offset within chunk
  const int row0 = blockIdx.x * 128;

  f32x4 acc[2][8];
  #pragma unroll
  for (int rt = 0; rt < 2; ++rt)
    #pragma unroll
    for (int ct = 0; ct < 8; ++ct) acc[rt][ct] = (f32x4)(0.f);

  for (int kc = 0; kc < 4; ++kc) {
    const int k0 = kc * 32;
    // stage A chunk: fp32 -> hi/lo bf16
    #pragma unroll
    for (int i = 0; i < 4; ++i) {
      const int idx = i * 256 + t;           // 1024 float4 slots: 128 rows x 8 quads
      const int r = idx >> 3, kq = idx & 7;
      const int gr = row0 + r;
      float4 v = make_float4(0.f, 0.f, 0.f, 0.f);
      if (gr < NN) v = *(const float4*)(A + (size_t)gr * D + k0 + kq * 4);
      const unsigned short h0 = f2bf_rn(v.x), h1 = f2bf_rn(v.y),
                           h2 = f2bf_rn(v.z), h3 = f2bf_rn(v.w);
      const unsigned short l0 = f2bf_rn(v.x - bf2f(h0)), l1 = f2bf_rn(v.y - bf2f(h1)),
                           l2 = f2bf_rn(v.z - bf2f(h2)), l3 = f2bf_rn(v.w - bf2f(h3));
      const unsigned long long hp = (unsigned long long)h0 | ((unsigned long long)h1 << 16) |
                                    ((unsigned long long)h2 << 32) | ((unsigned long long)h3 << 48);
      const unsigned long long lp = (unsigned long long)l0 | ((unsigned long long)l1 << 16) |
                                    ((unsigned long long)l2 << 32) | ((unsigned long long)l3 << 48);
      *(unsigned long long*)(sAh + r * 40 + kq * 4) = hp;
      *(unsigned long long*)(sAl + r * 40 + kq * 4) = lp;
    }
    // stage B chunk (pre-split, pre-padded: contiguous 10240 B per plane)
    {
      const u64x2* __restrict__ gh = (const u64x2*)(WhT + kc * (128 * 40));
      const u64x2* __restrict__ gl = (const u64x2*)(WlT + kc * (128 * 40));
      for (int i = t; i < 640; i += 256) {
        ((u64x2*)sBh)[i] = gh[i];
        ((u64x2*)sBl)[i] = gl[i];
      }
    }
    __syncthreads();

    const short8 ah0 = *(const short8*)(sAh + (w * 32 + 0 + lr) * 40 + lk);
    const short8 ah1 = *(const short8*)(sAh + (w * 32 + 16 + lr) * 40 + lk);
    const short8 al0 = *(const short8*)(sAl + (w * 32 + 0 + lr) * 40 + lk);
    const short8 al1 = *(const short8*)(sAl + (w * 32 + 16 + lr) * 40 + lk);
    #pragma unroll
    for (int ct = 0; ct < 8; ++ct) {
      const short8 bh = *(const short8*)(sBh + (ct * 16 + lr) * 40 + lk);
      const short8 bl = *(const short8*)(sBl + (ct * 16 + lr) * 40 + lk);
      acc[0][ct] = __builtin_amdgcn_mfma_f32_16x16x32_bf16(ah0, bh, acc[0][ct], 0, 0, 0);
      acc[0][ct] = __builtin_amdgcn_mfma_f32_16x16x32_bf16(al0, bh, acc[0][ct], 0, 0, 0);
      acc[0][ct] = __builtin_amdgcn_mfma_f32_16x16x32_bf16(ah0, bl, acc[0][ct], 0, 0, 0);
      acc[1][ct] = __builtin_amdgcn_mfma_f32_16x16x32_bf16(ah1, bh, acc[1][ct], 0, 0, 0);
      acc[1][ct] = __builtin_amdgcn_mfma_f32_16x16x32_bf16(al1, bh, acc[1][ct], 0, 0, 0);
      acc[1][ct] = __builtin_amdgcn_mfma_f32_16x16x32_bf16(ah1, bl, acc[1][ct], 0, 0, 0);
    }
    __syncthreads();
  }

  // epilogue: bias (+ReLU) + store (+BN stats partials)
  float bcol[8];
  #pragma unroll
  for (int ct = 0; ct < 8; ++ct) bcol[ct] = bias[ct * 16 + lr];
  float ps[8], pq[8];
  #pragma unroll
  for (int ct = 0; ct < 8; ++ct) { ps[ct] = 0.f; pq[ct] = 0.f; }

  #pragma unroll
  for (int rt = 0; rt < 2; ++rt) {
    #pragma unroll
    for (int j = 0; j < 4; ++j) {
      const int gr = row0 + w * 32 + rt * 16 + (l >> 4) * 4 + j;
      if (gr < NN) {
        #pragma unroll
        for (int ct = 0; ct < 8; ++ct) {
          float v = acc[rt][ct][j] + bcol[ct];
          if (RELU) v = fmaxf(v, 0.f);
          C[(size_t)gr * D + ct * 16 + lr] = v;
          if (STATS) { ps[ct] += v; pq[ct] += v * v; }
        }
      }
    }
  }

  if (STATS) {
    __syncthreads();
    float* red  = (float*)SMEM;            // [16][128]
    float* redq = red + 2048;
    const int grp = w * 4 + (l >> 4);
    #pragma unroll
    for (int ct = 0; ct < 8; ++ct) {
      red [grp * 128 + ct * 16 + lr] = ps[ct];
      redq[grp * 128 + ct * 16 + lr] = pq[ct];
    }
    __syncthreads();
    if (t < 128) {
      float s = 0.f, q = 0.f;
      #pragma unroll
      for (int g2 = 0; g2 < 16; ++g2) { s += red[g2 * 128 + t]; q += redq[g2 * 128 + t]; }
      atomicAdd(&sums[t], s);
      atomicAdd(&sumsq[t], q);
    }
  }
}

// ---------------- BN stat finalize ----------------
__global__ void k_stats(const float* __restrict__ sums, const float* __restrict__ sumsq,
                        const float* __restrict__ g, const float* __restrict__ beta,
                        float* __restrict__ scale, float* __restrict__ shift) {
  const int c = threadIdx.x;
  const float m   = sums[c] / (float)NN;
  const float var = sumsq[c] / (float)NN - m * m;
  const float sc  = g[c] / sqrtf(var + BN_EPS);
  scale[c] = sc;
  shift[c] = beta[c] - m * sc;
}

// ---------------- pooling (BN+ReLU applied on the fly; division folded into fc1) ----------------
__global__ __launch_bounds__(256) void k_pool(const float* __restrict__ T,
                                              const float* __restrict__ scale,
                                              const float* __restrict__ shift,
                                              const int* __restrict__ gstart,
                                              float* __restrict__ pooled, int lofs) {
  const int g = blockIdx.y;
  const int s = gstart[g], e = gstart[g + 1];
  const int t = threadIdx.x, c = t & 127, half = t >> 7;
  const float sc = scale[c], sh = shift[c];
  const int len = e - s;
  const int nchunk = (int)gridDim.x;
  const int per = (len + nchunk - 1) / nchunk;
  const int r0 = s + (int)blockIdx.x * per;
  const int r1 = min(e, r0 + per);
  float sum = 0.f;
  for (int r = r0 + half; r < r1; r += 2) sum += fmaxf(fmaf(T[r * D + c], sc, sh), 0.f);
  __shared__ float red[256];
  red[t] = sum;
  __syncthreads();
  if (t < 128) atomicAdd(&pooled[g * 384 + lofs + c], red[t] + red[t + 128]);
}

// ---------------- prediction head ----------------
__global__ __launch_bounds__(128) void k_fc1(const float* __restrict__ pooled,
                                             const int* __restrict__ gstart,
                                             const float* __restrict__ W1,
                                             const float* __restrict__ b1,
                                             float* __restrict__ z1) {
  const int g = blockIdx.x, j = threadIdx.x;
  __shared__ float p[384];
  const float cnt = (float)(gstart[g + 1] - gstart[g]);
  const float inv = 1.f / fmaxf(cnt, 1.f);
  for (int k = j; k < 384; k += 128) p[k] = pooled[g * 384 + k] * inv;
  __syncthreads();
  float acc = b1[j];
  #pragma unroll 8
  for (int k = 0; k < 384; ++k) acc = fmaf(p[k], W1[k * 128 + j], acc);
  z1[g * 128 + j] = fmaxf(acc, 0.f);
}

__global__ __launch_bounds__(128) void k_head(const float* __restrict__ z1,
                                              const float* __restrict__ g,
                                              const float* __restrict__ beta,
                                              const float* __restrict__ W2,
                                              const float* __restrict__ b2,
                                              float* __restrict__ out) {
  __shared__ float z2[NG][129];
  __shared__ float w2s[128];
  const int j = threadIdx.x;
  w2s[j] = W2[j];
  float vals[NG];
  float s = 0.f, q = 0.f;
  for (int gg = 0; gg < NG; ++gg) {
    float v = z1[gg * 128 + j];
    vals[gg] = v; s += v; q += v * v;
  }
  const float m   = s / (float)NG;
  const float var = q / (float)NG - m * m;
  const float sc  = g[j] / sqrtf(var + BN_EPS);
  const float sh  = beta[j] - m * sc;
  for (int gg = 0; gg < NG; ++gg) z2[gg][j] = vals[gg] * sc + sh;
  __syncthreads();
  if (j < NG) {
    float acc = b2[0];
    #pragma unroll 8
    for (int k = 0; k < 128; ++k) acc += z2[j][k] * w2s[k];
    out[j] = acc;
  }
}

// ---------------- launch ----------------
extern "C" void kernel_launch(void* const* d_in, const int* in_sizes, int n_in,
                              void* d_out, int out_size, void* d_ws, size_t ws_size,
                              hipStream_t stream) {
  const float* x     = (const float*)d_in[0];
  const int*   e_src = (const int*)d_in[1];
  const int*   e_dst = e_src + NE;
  const int*   batch = (const int*)d_in[2];
  const float *lW1[3], *lb1[3], *lW2[3], *lb2[3], *lg[3], *lbeta[3];
  for (int l = 0; l < 3; ++l) {
    lW1[l]   = (const float*)d_in[3 + 6 * l + 0];
    lb1[l]   = (const float*)d_in[3 + 6 * l + 1];
    lW2[l]   = (const float*)d_in[3 + 6 * l + 2];
    lb2[l]   = (const float*)d_in[3 + 6 * l + 3];
    lg[l]    = (const float*)d_in[3 + 6 * l + 4];
    lbeta[l] = (const float*)d_in[3 + 6 * l + 5];
  }
  const float* pW1   = (const float*)d_in[21];
  const float* pb1   = (const float*)d_in[22];
  const float* pg    = (const float*)d_in[23];
  const float* pbeta = (const float*)d_in[24];
  const float* pW2   = (const float*)d_in[25];
  const float* pb2   = (const float*)d_in[26];
  float* out = (float*)d_out;

  char* w = (char*)d_ws;
  auto alloc = [&](size_t bytes) { char* p = w; w += (bytes + 255) & ~(size_t)255; return p; };
  float* P      = (float*)alloc((size_t)NN * D * 4);
  float* Q      = (float*)alloc((size_t)NN * D * 4);
  int*   counts = (int*)alloc((size_t)NN * 4);
  int*   cursor = (int*)alloc((size_t)NN * 4);
  int*   offs   = (int*)alloc((size_t)(NN + 1) * 4);
  int*   esrc   = (int*)alloc((size_t)NE * 4);
  int*   gstart = (int*)alloc((size_t)(NG + 1) * 4);
  float* stats  = (float*)alloc((size_t)4 * 128 * 4);
  float* sums = stats, *sumsq = stats + 128, *scale = stats + 256, *shift = stats + 384;
  float* pooled = (float*)alloc((size_t)NG * 384 * 4);
  float* z1     = (float*)alloc((size_t)NG * 128 * 4);
  short* wb     = (short*)alloc((size_t)12 * 40960);   // 12 planes of [4][128][40] shorts

  hipMemsetAsync(counts, 0, (size_t)NN * 4, stream);
  hipMemsetAsync(cursor, 0, (size_t)NN * 4, stream);
  hipMemsetAsync(pooled, 0, (size_t)NG * 384 * 4, stream);

  k_hist   <<<(NE + 255) / 256, 256, 0, stream>>>(e_dst, counts);
  k_scan   <<<1, 1024, 0, stream>>>(counts, offs);
  k_scatter<<<(NE + 255) / 256, 256, 0, stream>>>(e_src, e_dst, offs, cursor, esrc);
  k_gbounds<<<1, 128, 0, stream>>>(batch, gstart);

  short* Wp[12];
  for (int i = 0; i < 12; ++i) Wp[i] = wb + (size_t)i * 20480;
  for (int l = 0; l < 3; ++l) {
    k_prep<<<1, 256, 0, stream>>>(lW1[l], Wp[l * 4 + 0], Wp[l * 4 + 1]);
    k_prep<<<1, 256, 0, stream>>>(lW2[l], Wp[l * 4 + 2], Wp[l * 4 + 3]);
  }

  const int gemm_grid = (NN + 127) / 128;
  float* buf[2] = {Q, P};
  for (int l = 0; l < 3; ++l) {
    float* T = buf[l & 1];           // this layer's working buffer
    if (l == 0)
      k_aggregate<false><<<NN / 4, 256, 0, stream>>>(x, offs, esrc, nullptr, nullptr, T);
    else
      k_aggregate<true><<<NN / 4, 256, 0, stream>>>(buf[(l - 1) & 1], offs, esrc, scale, shift, T);
    k_gemm_mfma<true, false><<<gemm_grid, 256, 0, stream>>>(T, Wp[l*4+0], Wp[l*4+1], lb1[l], T, nullptr, nullptr);
    hipMemsetAsync(sums, 0, 2 * 128 * 4, stream);
    k_gemm_mfma<false, true><<<gemm_grid, 256, 0, stream>>>(T, Wp[l*4+2], Wp[l*4+3], lb2[l], T, sums, sumsq);
    k_stats<<<1, 128, 0, stream>>>(sums, sumsq, lg[l], lbeta[l], scale, shift);
    k_pool <<<dim3(8, NG), 256, 0, stream>>>(T, scale, shift, gstart, pooled, l * 128);
  }

  k_fc1 <<<NG, 128, 0, stream>>>(pooled, gstart, pW1, pb1, z1);
  k_head<<<1, 128, 0, stream>>>(z1, pg, pbeta, pW2, pb2, out);
}

// Round 4
// 578.638 us; speedup vs baseline: 1.8026x; 1.0925x over previous
//
#include <hip/hip_runtime.h>

#define NN 50000
#define NE 800000
#define D  128
#define NG 64
#define BN_EPS 1e-5f

typedef __attribute__((ext_vector_type(8))) short short8;
typedef __attribute__((ext_vector_type(4))) float f32x4;
typedef __attribute__((ext_vector_type(2))) unsigned long long u64x2;

static __device__ inline unsigned short f2bf_rn(float f) {
  unsigned u = __float_as_uint(f);
  unsigned r = (u + 0x7FFF + ((u >> 16) & 1)) >> 16;
  return (unsigned short)r;
}
static __device__ inline float bf2f(unsigned short h) {
  return __uint_as_float((unsigned)h << 16);
}

// ---------------- CSR build ----------------
__global__ void k_hist(const int* __restrict__ dst, int* __restrict__ counts) {
  int e = blockIdx.x * blockDim.x + threadIdx.x;
  if (e < NE) atomicAdd(&counts[dst[e]], 1);
}

__global__ void k_scan(const int* __restrict__ counts, int* __restrict__ offs) {
  __shared__ int wsum[16];
  __shared__ int carry_s;
  const int t = threadIdx.x, lane = t & 63, w = t >> 6;
  if (t == 0) carry_s = 0;
  __syncthreads();
  for (int base = 0; base < NN; base += 1024) {
    int i = base + t;
    int v = (i < NN) ? counts[i] : 0;
    int s = v;
    #pragma unroll
    for (int d = 1; d < 64; d <<= 1) { int u = __shfl_up(s, d, 64); if (lane >= d) s += u; }
    if (lane == 63) wsum[w] = s;
    __syncthreads();
    if (w == 0 && lane < 16) {
      int ws = wsum[lane]; int ss = ws;
      #pragma unroll
      for (int d = 1; d < 16; d <<= 1) { int u = __shfl_up(ss, d, 64); if (lane >= d) ss += u; }
      wsum[lane] = ss - ws;
    }
    __syncthreads();
    int carry = carry_s;
    if (i < NN) offs[i] = carry + wsum[w] + (s - v);
    __syncthreads();
    if (t == 1023) carry_s = carry + wsum[15] + s;
    __syncthreads();
  }
  if (threadIdx.x == 0) offs[NN] = carry_s;
}

__global__ void k_scatter(const int* __restrict__ src, const int* __restrict__ dst,
                          const int* __restrict__ offs, int* __restrict__ cursor,
                          int* __restrict__ esrc) {
  int e = blockIdx.x * blockDim.x + threadIdx.x;
  if (e < NE) {
    int d = dst[e];
    int p = offs[d] + atomicAdd(&cursor[d], 1);
    esrc[p] = src[e];
  }
}

__global__ void k_gbounds(const int* __restrict__ batch, int* __restrict__ gstart) {
  const int g = threadIdx.x;
  if (g > NG) return;
  int lo = 0, hi = NN;
  while (lo < hi) { int mid = (lo + hi) >> 1; if (batch[mid] < g) lo = mid + 1; else hi = mid; }
  gstart[g] = lo;
}

// ---------------- x fp32 -> bf16 ----------------
__global__ __launch_bounds__(256) void k_cvt(const float* __restrict__ X,
                                             unsigned long long* __restrict__ Xb) {
  const int n4 = NN * D / 4;
  for (int i = blockIdx.x * blockDim.x + threadIdx.x; i < n4; i += gridDim.x * blockDim.x) {
    float4 v = ((const float4*)X)[i];
    unsigned long long p = (unsigned long long)f2bf_rn(v.x) |
                           ((unsigned long long)f2bf_rn(v.y) << 16) |
                           ((unsigned long long)f2bf_rn(v.z) << 32) |
                           ((unsigned long long)f2bf_rn(v.w) << 48);
    Xb[i] = p;
  }
}

// ---------------- weight prep: W[128][128] fp32 -> W^T hi/lo bf16, chunked+padded ----------------
// layout: [chunk(4)][col(128)][40] shorts; element (k,c) -> plane[(k>>5)*128+c][k&31].
__global__ void k_prep(const float* __restrict__ W, short* __restrict__ WhT,
                       short* __restrict__ WlT) {
  const int t = threadIdx.x;
  for (int i = 0; i < 64; ++i) {
    int idx = i * 256 + t;
    int k = idx >> 7, c = idx & 127;
    float v = W[idx];
    unsigned short h = f2bf_rn(v);
    unsigned short lo = f2bf_rn(v - bf2f(h));
    int o = ((k >> 5) * 128 + c) * 40 + (k & 31);
    WhT[o] = (short)h;
    WlT[o] = (short)lo;
  }
}

// ---------------- aggregation on bf16 rows (+ fused BN/ReLU of producer layer) ----------------
template<bool BN>
__global__ __launch_bounds__(256) void k_aggregate(const unsigned* __restrict__ Hb, // bf16x2 words
                                                   const int* __restrict__ offs,
                                                   const int* __restrict__ esrc,
                                                   const float* __restrict__ scale,
                                                   const float* __restrict__ shift,
                                                   unsigned* __restrict__ AGGb) {
  const int node = blockIdx.x * 4 + (threadIdx.x >> 6);
  const int lane = threadIdx.x & 63;
  float2 sc = make_float2(1.f, 1.f), sh = make_float2(0.f, 0.f);
  if (BN) { sc = ((const float2*)scale)[lane]; sh = ((const float2*)shift)[lane]; }

  auto rd = [&](int r) -> float2 {
    const unsigned u = Hb[r * 64 + lane];
    float2 v = make_float2(bf2f((unsigned short)u), bf2f((unsigned short)(u >> 16)));
    if (BN) {
      v.x = fmaxf(fmaf(v.x, sc.x, sh.x), 0.f);
      v.y = fmaxf(fmaf(v.y, sc.y, sh.y), 0.f);
    }
    return v;
  };

  float2 acc = rd(node);
  const int b = offs[node], e = offs[node + 1];
  int i = b;
  for (; i + 4 <= e; i += 4) {
    const int s0 = esrc[i], s1 = esrc[i + 1], s2 = esrc[i + 2], s3 = esrc[i + 3];
    const float2 v0 = rd(s0), v1 = rd(s1), v2 = rd(s2), v3 = rd(s3);
    acc.x += (v0.x + v1.x) + (v2.x + v3.x);
    acc.y += (v0.y + v1.y) + (v2.y + v3.y);
  }
  for (; i < e; ++i) {
    const float2 v = rd(esrc[i]);
    acc.x += v.x; acc.y += v.y;
  }
  AGGb[node * 64 + lane] = (unsigned)f2bf_rn(acc.x) | ((unsigned)f2bf_rn(acc.y) << 16);
}

// ---------------- fused MLP: H = (relu(A@W1+b1))@W2+b2, A bf16, W hi/lo bf16 ----------------
// 64 rows/block, 4 waves (16 rows each), 8 col-tiles. Stats for BN fused in epilogue.
__global__ __launch_bounds__(256) void k_mlp(const short* __restrict__ AGGb,
                                             const short* __restrict__ W1h, const short* __restrict__ W1l,
                                             const short* __restrict__ W2h, const short* __restrict__ W2l,
                                             const float* __restrict__ b1, const float* __restrict__ b2,
                                             short* __restrict__ Hb,
                                             float* __restrict__ sums, float* __restrict__ sumsq) {
  __shared__ __align__(16) short sA[64 * 136];          // A tile, then C1 tile
  __shared__ __align__(16) char WBUF[20480];            // W chunk hi+lo; reused for stats red
  short* sWh = (short*)WBUF;
  short* sWl = (short*)(WBUF + 10240);

  const int t = threadIdx.x;
  const int l = t & 63, w = t >> 6;
  const int lr = l & 15, fq = l >> 4;
  const int lk = fq * 8;
  const int row0 = blockIdx.x * 64;

  // stage A (bf16 copy): 64 rows x 16 quads of 8 shorts
  #pragma unroll
  for (int i = 0; i < 4; ++i) {
    const int idx = i * 256 + t;
    const int r = idx >> 4, q = idx & 15;
    const int gr = row0 + r;
    short8 v = (short8)(0);
    if (gr < NN) v = *(const short8*)(AGGb + (size_t)gr * D + q * 8);
    *(short8*)(sA + r * 136 + q * 8) = v;
  }

  // ---- GEMM1 ----
  f32x4 acc[8];
  #pragma unroll
  for (int ct = 0; ct < 8; ++ct) acc[ct] = (f32x4)(0.f);
  for (int kc = 0; kc < 4; ++kc) {
    const u64x2* __restrict__ gh = (const u64x2*)(W1h + kc * (128 * 40));
    const u64x2* __restrict__ gl = (const u64x2*)(W1l + kc * (128 * 40));
    for (int i = t; i < 640; i += 256) {
      ((u64x2*)sWh)[i] = gh[i];
      ((u64x2*)sWl)[i] = gl[i];
    }
    __syncthreads();
    const short8 a = *(const short8*)(sA + (w * 16 + lr) * 136 + kc * 32 + lk);
    #pragma unroll
    for (int ct = 0; ct < 8; ++ct) {
      const short8 bh = *(const short8*)(sWh + (ct * 16 + lr) * 40 + lk);
      const short8 bl = *(const short8*)(sWl + (ct * 16 + lr) * 40 + lk);
      acc[ct] = __builtin_amdgcn_mfma_f32_16x16x32_bf16(a, bh, acc[ct], 0, 0, 0);
      acc[ct] = __builtin_amdgcn_mfma_f32_16x16x32_bf16(a, bl, acc[ct], 0, 0, 0);
    }
    __syncthreads();
  }

  // ---- C1 = relu(acc+b1) -> bf16 -> sA (D-layout -> row-major) ----
  #pragma unroll
  for (int ct = 0; ct < 8; ++ct) {
    const float bb = b1[ct * 16 + lr];
    #pragma unroll
    for (int j = 0; j < 4; ++j) {
      const int r = w * 16 + fq * 4 + j;
      sA[r * 136 + ct * 16 + lr] = (short)f2bf_rn(fmaxf(acc[ct][j] + bb, 0.f));
    }
  }
  __syncthreads();

  // ---- GEMM2 ----
  f32x4 acc2[8];
  #pragma unroll
  for (int ct = 0; ct < 8; ++ct) acc2[ct] = (f32x4)(0.f);
  for (int kc = 0; kc < 4; ++kc) {
    const u64x2* __restrict__ gh = (const u64x2*)(W2h + kc * (128 * 40));
    const u64x2* __restrict__ gl = (const u64x2*)(W2l + kc * (128 * 40));
    for (int i = t; i < 640; i += 256) {
      ((u64x2*)sWh)[i] = gh[i];
      ((u64x2*)sWl)[i] = gl[i];
    }
    __syncthreads();
    const short8 a = *(const short8*)(sA + (w * 16 + lr) * 136 + kc * 32 + lk);
    #pragma unroll
    for (int ct = 0; ct < 8; ++ct) {
      const short8 bh = *(const short8*)(sWh + (ct * 16 + lr) * 40 + lk);
      const short8 bl = *(const short8*)(sWl + (ct * 16 + lr) * 40 + lk);
      acc2[ct] = __builtin_amdgcn_mfma_f32_16x16x32_bf16(a, bh, acc2[ct], 0, 0, 0);
      acc2[ct] = __builtin_amdgcn_mfma_f32_16x16x32_bf16(a, bl, acc2[ct], 0, 0, 0);
    }
    __syncthreads();
  }

  // ---- epilogue: +b2, store bf16 H (pre-BN), BN stats partials ----
  float ps[8], pq[8];
  #pragma unroll
  for (int ct = 0; ct < 8; ++ct) { ps[ct] = 0.f; pq[ct] = 0.f; }
  #pragma unroll
  for (int ct = 0; ct < 8; ++ct) {
    const float bb = b2[ct * 16 + lr];
    #pragma unroll
    for (int j = 0; j < 4; ++j) {
      const int gr = row0 + w * 16 + fq * 4 + j;
      if (gr < NN) {
        const float v = acc2[ct][j] + bb;
        Hb[(size_t)gr * D + ct * 16 + lr] = (short)f2bf_rn(v);
        ps[ct] += v; pq[ct] += v * v;
      }
    }
  }
  // reduce stats: 16 groups x 128 cols in WBUF
  float* red  = (float*)WBUF;          // [16][128] = 8 KB
  float* redq = red + 2048;            // 8 KB (total 16 KB <= 20480)
  const int grp = w * 4 + fq;
  #pragma unroll
  for (int ct = 0; ct < 8; ++ct) {
    red [grp * 128 + ct * 16 + lr] = ps[ct];
    redq[grp * 128 + ct * 16 + lr] = pq[ct];
  }
  __syncthreads();
  if (t < 128) {
    float s = 0.f, q = 0.f;
    #pragma unroll
    for (int g2 = 0; g2 < 16; ++g2) { s += red[g2 * 128 + t]; q += redq[g2 * 128 + t]; }
    atomicAdd(&sums[t], s);
    atomicAdd(&sumsq[t], q);
  }
}

// ---------------- BN stat finalize ----------------
__global__ void k_stats(const float* __restrict__ sums, const float* __restrict__ sumsq,
                        const float* __restrict__ g, const float* __restrict__ beta,
                        float* __restrict__ scale, float* __restrict__ shift) {
  const int c = threadIdx.x;
  const float m   = sums[c] / (float)NN;
  const float var = sumsq[c] / (float)NN - m * m;
  const float sc  = g[c] / sqrtf(var + BN_EPS);
  scale[c] = sc;
  shift[c] = beta[c] - m * sc;
}

// ---------------- pooling (BN+ReLU on the fly; division folded into fc1) ----------------
__global__ __launch_bounds__(256) void k_pool(const unsigned short* __restrict__ Hb,
                                              const float* __restrict__ scale,
                                              const float* __restrict__ shift,
                                              const int* __restrict__ gstart,
                                              float* __restrict__ pooled, int lofs) {
  const int g = blockIdx.y;
  const int s = gstart[g], e = gstart[g + 1];
  const int t = threadIdx.x, c = t & 127, half = t >> 7;
  const float sc = scale[c], sh = shift[c];
  const int len = e - s;
  const int nchunk = (int)gridDim.x;
  const int per = (len + nchunk - 1) / nchunk;
  const int r0 = s + (int)blockIdx.x * per;
  const int r1 = min(e, r0 + per);
  float sum = 0.f;
  for (int r = r0 + half; r < r1; r += 2)
    sum += fmaxf(fmaf(bf2f(Hb[r * D + c]), sc, sh), 0.f);
  __shared__ float red[256];
  red[t] = sum;
  __syncthreads();
  if (t < 128) atomicAdd(&pooled[g * 384 + lofs + c], red[t] + red[t + 128]);
}

// ---------------- prediction head ----------------
__global__ __launch_bounds__(128) void k_fc1(const float* __restrict__ pooled,
                                             const int* __restrict__ gstart,
                                             const float* __restrict__ W1,
                                             const float* __restrict__ b1,
                                             float* __restrict__ z1) {
  const int g = blockIdx.x, j = threadIdx.x;
  __shared__ float p[384];
  const float cnt = (float)(gstart[g + 1] - gstart[g]);
  const float inv = 1.f / fmaxf(cnt, 1.f);
  for (int k = j; k < 384; k += 128) p[k] = pooled[g * 384 + k] * inv;
  __syncthreads();
  float acc = b1[j];
  #pragma unroll 8
  for (int k = 0; k < 384; ++k) acc = fmaf(p[k], W1[k * 128 + j], acc);
  z1[g * 128 + j] = fmaxf(acc, 0.f);
}

__global__ __launch_bounds__(128) void k_head(const float* __restrict__ z1,
                                              const float* __restrict__ g,
                                              const float* __restrict__ beta,
                                              const float* __restrict__ W2,
                                              const float* __restrict__ b2,
                                              float* __restrict__ out) {
  __shared__ float z2[NG][129];
  __shared__ float w2s[128];
  const int j = threadIdx.x;
  w2s[j] = W2[j];
  float vals[NG];
  float s = 0.f, q = 0.f;
  for (int gg = 0; gg < NG; ++gg) {
    float v = z1[gg * 128 + j];
    vals[gg] = v; s += v; q += v * v;
  }
  const float m   = s / (float)NG;
  const float var = q / (float)NG - m * m;
  const float sc  = g[j] / sqrtf(var + BN_EPS);
  const float sh  = beta[j] - m * sc;
  for (int gg = 0; gg < NG; ++gg) z2[gg][j] = vals[gg] * sc + sh;
  __syncthreads();
  if (j < NG) {
    float acc = b2[0];
    #pragma unroll 8
    for (int k = 0; k < 128; ++k) acc += z2[j][k] * w2s[k];
    out[j] = acc;
  }
}

// ---------------- launch ----------------
extern "C" void kernel_launch(void* const* d_in, const int* in_sizes, int n_in,
                              void* d_out, int out_size, void* d_ws, size_t ws_size,
                              hipStream_t stream) {
  const float* x     = (const float*)d_in[0];
  const int*   e_src = (const int*)d_in[1];
  const int*   e_dst = e_src + NE;
  const int*   batch = (const int*)d_in[2];
  const float *lW1[3], *lb1[3], *lW2[3], *lb2[3], *lg[3], *lbeta[3];
  for (int l = 0; l < 3; ++l) {
    lW1[l]   = (const float*)d_in[3 + 6 * l + 0];
    lb1[l]   = (const float*)d_in[3 + 6 * l + 1];
    lW2[l]   = (const float*)d_in[3 + 6 * l + 2];
    lb2[l]   = (const float*)d_in[3 + 6 * l + 3];
    lg[l]    = (const float*)d_in[3 + 6 * l + 4];
    lbeta[l] = (const float*)d_in[3 + 6 * l + 5];
  }
  const float* pW1   = (const float*)d_in[21];
  const float* pb1   = (const float*)d_in[22];
  const float* pg    = (const float*)d_in[23];
  const float* pbeta = (const float*)d_in[24];
  const float* pW2   = (const float*)d_in[25];
  const float* pb2   = (const float*)d_in[26];
  float* out = (float*)d_out;

  char* w = (char*)d_ws;
  auto alloc = [&](size_t bytes) { char* p = w; w += (bytes + 255) & ~(size_t)255; return p; };
  short* xb     = (short*)alloc((size_t)NN * D * 2);
  short* AGGb   = (short*)alloc((size_t)NN * D * 2);
  short* Hb0    = (short*)alloc((size_t)NN * D * 2);
  short* Hb1    = (short*)alloc((size_t)NN * D * 2);
  int*   counts = (int*)alloc((size_t)NN * 4);
  int*   cursor = (int*)alloc((size_t)NN * 4);
  int*   offs   = (int*)alloc((size_t)(NN + 1) * 4);
  int*   esrc   = (int*)alloc((size_t)NE * 4);
  int*   gstart = (int*)alloc((size_t)(NG + 1) * 4);
  float* stats  = (float*)alloc((size_t)4 * 128 * 4);
  float* sums = stats, *sumsq = stats + 128, *scale = stats + 256, *shift = stats + 384;
  float* pooled = (float*)alloc((size_t)NG * 384 * 4);
  float* z1     = (float*)alloc((size_t)NG * 128 * 4);
  short* wb     = (short*)alloc((size_t)12 * 40960);

  hipMemsetAsync(counts, 0, (size_t)NN * 4, stream);
  hipMemsetAsync(cursor, 0, (size_t)NN * 4, stream);
  hipMemsetAsync(pooled, 0, (size_t)NG * 384 * 4, stream);

  k_hist   <<<(NE + 255) / 256, 256, 0, stream>>>(e_dst, counts);
  k_scan   <<<1, 1024, 0, stream>>>(counts, offs);
  k_scatter<<<(NE + 255) / 256, 256, 0, stream>>>(e_src, e_dst, offs, cursor, esrc);
  k_gbounds<<<1, 128, 0, stream>>>(batch, gstart);
  k_cvt    <<<1024, 256, 0, stream>>>(x, (unsigned long long*)xb);

  short* Wp[12];
  for (int i = 0; i < 12; ++i) Wp[i] = wb + (size_t)i * 20480;
  for (int l = 0; l < 3; ++l) {
    k_prep<<<1, 256, 0, stream>>>(lW1[l], Wp[l * 4 + 0], Wp[l * 4 + 1]);
    k_prep<<<1, 256, 0, stream>>>(lW2[l], Wp[l * 4 + 2], Wp[l * 4 + 3]);
  }

  short* Hbuf[2] = {Hb0, Hb1};
  const int mlp_grid = (NN + 63) / 64;
  for (int l = 0; l < 3; ++l) {
    if (l == 0)
      k_aggregate<false><<<NN / 4, 256, 0, stream>>>((const unsigned*)xb, offs, esrc, nullptr, nullptr, (unsigned*)AGGb);
    else
      k_aggregate<true><<<NN / 4, 256, 0, stream>>>((const unsigned*)Hbuf[(l - 1) & 1], offs, esrc, scale, shift, (unsigned*)AGGb);
    hipMemsetAsync(sums, 0, 2 * 128 * 4, stream);
    k_mlp<<<mlp_grid, 256, 0, stream>>>(AGGb, Wp[l*4+0], Wp[l*4+1], Wp[l*4+2], Wp[l*4+3],
                                        lb1[l], lb2[l], Hbuf[l & 1], sums, sumsq);
    k_stats<<<1, 128, 0, stream>>>(sums, sumsq, lg[l], lbeta[l], scale, shift);
    k_pool <<<dim3(8, NG), 256, 0, stream>>>((const unsigned short*)Hbuf[l & 1], scale, shift, gstart, pooled, l * 128);
  }

  k_fc1 <<<NG, 128, 0, stream>>>(pooled, gstart, pW1, pb1, z1);
  k_head<<<1, 128, 0, stream>>>(z1, pg, pbeta, pW2, pb2, out);
}